// Round 11
// baseline (192.100 us; speedup 1.0000x reference)
//
#include <hip/hip_runtime.h>
#include <hip/hip_bf16.h>
#include <stdint.h>

typedef unsigned short u16;
typedef __attribute__((ext_vector_type(8))) short short8;
typedef __attribute__((ext_vector_type(4))) float f32x4;
typedef __attribute__((ext_vector_type(2))) float f32x2;

__device__ __forceinline__ u16 f2bf(float f) {
    union { float f; unsigned int i; } v; v.f = f;
    unsigned int b = v.i;
    return (u16)((b + 0x7FFFu + ((b >> 16) & 1u)) >> 16);
}

__device__ __forceinline__ short8 cvt8(float4 a, float4 b) {
    union { __hip_bfloat162 h[4]; short8 s; } u;
    u.h[0] = __float22bfloat162_rn(make_float2(a.x, a.y));
    u.h[1] = __float22bfloat162_rn(make_float2(a.z, a.w));
    u.h[2] = __float22bfloat162_rn(make_float2(b.x, b.y));
    u.h[3] = __float22bfloat162_rn(make_float2(b.z, b.w));
    return u.s;
}

typedef const __attribute__((address_space(1))) void* as1cv;
typedef __attribute__((address_space(3))) void* as3v;
__device__ __forceinline__ void gload16(const void* g, void* l) {
    __builtin_amdgcn_global_load_lds((as1cv)g, (as3v)l, 16, 0, 0);
}

__device__ __forceinline__ void up2(unsigned int v, float& lo, float& hi) {
    union { unsigned int i; float f; } a, b;
    a.i = v << 16; b.i = v & 0xffff0000u;
    lo = a.f; hi = b.f;
}

// ---------------------------------------------------------------------------
// wprep: weight convert fp32 -> bf16, transposed. (verbatim R13, known-good)
// ---------------------------------------------------------------------------
__global__ __launch_bounds__(256) void wprep(
    const float* __restrict__ W0, const float* __restrict__ W1,
    const float* __restrict__ W2, const float* __restrict__ W3,
    u16* __restrict__ T0, u16* __restrict__ T1,
    u16* __restrict__ T2, u16* __restrict__ T3)
{
    const float* W = blockIdx.z == 0 ? W0 : blockIdx.z == 1 ? W1 : blockIdx.z == 2 ? W2 : W3;
    u16*        T  = blockIdx.z == 0 ? T0 : blockIdx.z == 1 ? T1 : blockIdx.z == 2 ? T2 : T3;
    __shared__ u16 ts[64][65];
    int k0 = blockIdx.x * 64, n0 = blockIdx.y * 64;
    int t = threadIdx.x;
    int r = t >> 2, cq = (t & 3) * 16;
    const float4* src = reinterpret_cast<const float4*>(W + (k0 + r) * 256 + n0 + cq);
    for (int u = 0; u < 4; ++u) {
        float4 v = src[u];
        int c = cq + u * 4;
        ts[r][c + 0] = f2bf(v.x); ts[r][c + 1] = f2bf(v.y);
        ts[r][c + 2] = f2bf(v.z); ts[r][c + 3] = f2bf(v.w);
    }
    __syncthreads();
    u16* dst = T + (n0 + r) * 256 + k0 + cq;
    for (int u = 0; u < 16; ++u) dst[u] = ts[cq + u][r];
}

// ---------------------------------------------------------------------------
// gemm_proj (R21): same tile as R13 (BM=64, BN=256, BK=64), but K and V
// projections are written as FP32 (removes 128 bf16-unpack VALU ops per attn
// job — attn is measured VALU-bound at 87% busy). Q stays bf16.
// ---------------------------------------------------------------------------
__global__ __launch_bounds__(256) void gemm_proj(
    const float* __restrict__ Q, const float* __restrict__ K,
    const u16* __restrict__ Wtq, const u16* __restrict__ Wtk, const u16* __restrict__ Wtv,
    const float* __restrict__ bq, const float* __restrict__ bk, const float* __restrict__ bv,
    u16* __restrict__ Qh, float* __restrict__ Khf, float* __restrict__ Vhf)
{
    int z = blockIdx.z;
    const float* Af   = (z == 0) ? Q   : K;
    const u16*   Wt   = (z == 0) ? Wtq : (z == 1) ? Wtk : Wtv;
    const float* bias = (z == 0) ? bq  : (z == 1) ? bk  : bv;

    __shared__ float Asf[64 * 64];    // 16 KB
    __shared__ u16   Bs[256 * 64];    // 32 KB

    int t = threadIdx.x;
    int lane = t & 63, w = t >> 6;
    int row0 = blockIdx.x * 64;
    int wr = (w >> 1) * 32, wc = (w & 1) * 128;
    int qd = lane >> 4, md = lane & 15;

    f32x4 acc[2][8] = {};

    for (int kt = 0; kt < 256; kt += 64) {
#pragma unroll
        for (int u = 0; u < 4; ++u) {
            int chunk = w * 4 + u;
            int s = chunk * 64 + lane;
            int r = s >> 4, c = s & 15;
            gload16(Af + (size_t)(row0 + r) * 256 + kt + ((c ^ (r & 15)) * 4),
                    (char*)Asf + chunk * 1024);
        }
#pragma unroll
        for (int u = 0; u < 8; ++u) {
            int chunk = w * 8 + u;
            int s = chunk * 64 + lane;
            int r = s >> 3, c = s & 7;
            gload16(Wt + (size_t)r * 256 + kt + ((c ^ (r & 7)) * 8),
                    (char*)Bs + chunk * 1024);
        }
        __syncthreads();
#pragma unroll
        for (int ks = 0; ks < 64; ks += 32) {
            short8 af[2], bf[8];
#pragma unroll
            for (int i = 0; i < 2; ++i) {
                int ar = wr + i * 16 + md;
                int c0 = (ks >> 2) + qd * 2;
                int xx = ar & 15;
                float4 fa0 = reinterpret_cast<const float4*>(Asf)[ar * 16 + (c0 ^ xx)];
                float4 fa1 = reinterpret_cast<const float4*>(Asf)[ar * 16 + ((c0 + 1) ^ xx)];
                af[i] = cvt8(fa0, fa1);
            }
#pragma unroll
            for (int j = 0; j < 8; ++j) {
                int br = wc + j * 16 + md;
                int slot = ((ks >> 3) + qd) ^ (br & 7);
                bf[j] = reinterpret_cast<const short8*>(Bs)[br * 8 + slot];
            }
#pragma unroll
            for (int i = 0; i < 2; ++i)
#pragma unroll
                for (int j = 0; j < 8; ++j)
                    acc[i][j] = __builtin_amdgcn_mfma_f32_16x16x32_bf16(
                        af[i], bf[j], acc[i][j], 0, 0, 0);
        }
        __syncthreads();
    }

#pragma unroll
    for (int i = 0; i < 2; ++i)
#pragma unroll
        for (int j = 0; j < 8; ++j) {
            int col = wc + j * 16 + md;
            float b = bias[col];
#pragma unroll
            for (int r = 0; r < 4; ++r) {
                int row = row0 + wr + i * 16 + qd * 4 + r;
                float v = acc[i][j][r] + b;
                if (z == 0)      Qh [(size_t)row * 256 + col] = f2bf(v);
                else if (z == 1) Khf[(size_t)row * 256 + col] = v;
                else             Vhf[(size_t)row * 256 + col] = v;
            }
        }
}

// ---------------------------------------------------------------------------
// gemm_out: f32 C = bf16 A @ Wt^T + bias. 64x128 tile. (verbatim R13)
// ---------------------------------------------------------------------------
__global__ __launch_bounds__(256) void gemm_out(
    const u16* __restrict__ Ab, const u16* __restrict__ Wt,
    const float* __restrict__ bias, float* __restrict__ Cout)
{
    __shared__ u16 As[64 * 64];
    __shared__ u16 Bs[128 * 64];

    int t = threadIdx.x;
    int lane = t & 63, w = t >> 6;
    int row0 = blockIdx.x * 64, col0 = blockIdx.y * 128;
    int wr = (w >> 1) * 32, wc = (w & 1) * 64;
    int qd = lane >> 4, md = lane & 15;

    f32x4 acc[2][4] = {};

    for (int kt = 0; kt < 256; kt += 64) {
#pragma unroll
        for (int u = 0; u < 2; ++u) {
            int chunk = w * 2 + u;
            int s = chunk * 64 + lane;
            int r = s >> 3, c = s & 7;
            gload16(Ab + (size_t)(row0 + r) * 256 + kt + ((c ^ (r & 7)) * 8),
                    (char*)As + chunk * 1024);
        }
#pragma unroll
        for (int u = 0; u < 4; ++u) {
            int chunk = w * 4 + u;
            int s = chunk * 64 + lane;
            int r = s >> 3, c = s & 7;
            gload16(Wt + (size_t)(col0 + r) * 256 + kt + ((c ^ (r & 7)) * 8),
                    (char*)Bs + chunk * 1024);
        }
        __syncthreads();
#pragma unroll
        for (int ks = 0; ks < 64; ks += 32) {
            short8 af[2], bf[4];
#pragma unroll
            for (int i = 0; i < 2; ++i) {
                int ar = wr + i * 16 + md;
                int slot = ((ks >> 3) + qd) ^ (ar & 7);
                af[i] = reinterpret_cast<const short8*>(As)[ar * 8 + slot];
            }
#pragma unroll
            for (int j = 0; j < 4; ++j) {
                int br = wc + j * 16 + md;
                int slot = ((ks >> 3) + qd) ^ (br & 7);
                bf[j] = reinterpret_cast<const short8*>(Bs)[br * 8 + slot];
            }
#pragma unroll
            for (int i = 0; i < 2; ++i)
#pragma unroll
                for (int j = 0; j < 4; ++j)
                    acc[i][j] = __builtin_amdgcn_mfma_f32_16x16x32_bf16(
                        af[i], bf[j], acc[i][j], 0, 0, 0);
        }
        __syncthreads();
    }

#pragma unroll
    for (int i = 0; i < 2; ++i)
#pragma unroll
        for (int j = 0; j < 4; ++j) {
            int col = col0 + wc + j * 16 + md;
            float b = bias[col];
#pragma unroll
            for (int r = 0; r < 4; ++r) {
                int row = row0 + wr + i * 16 + qd * 4 + r;
                Cout[(size_t)row * 256 + col] = acc[i][j][r] + b;
            }
        }
}

// ---------------------------------------------------------------------------
// attn row mapping: (batch, head-half) classes spread 2 XCDs each. (R13)
// ---------------------------------------------------------------------------
__device__ __forceinline__ void attn_map2(int blk, int w, int& row, int& hf) {
    int g = blk & 7;
    int batch = g >> 2;
    hf = (g >> 1) & 1;
    int cb = (blk >> 3) * 2 + (g & 1);
    row = batch * 8192 + cb * 4 + w;
}

// ---------------------------------------------------------------------------
// attn_fused (R21): R13 structure, but K/V gathered as FP32 (no unpack ops)
// and score/AV math in f32x2 packed pairs (backend: v_pk_fma_f32). R20
// counters showed VALUBusy 87% / HBM 20% -> attn is VALU-bound; this cuts
// the inner-loop VALU count from ~256 to ~105 ops per job.
// ---------------------------------------------------------------------------
__global__ __launch_bounds__(256) void attn_fused(
    const u16* __restrict__ Qh, const float* __restrict__ Khf,
    const float* __restrict__ Vhf, const int* __restrict__ nbr,
    u16* __restrict__ AVb)
{
    __shared__ int jbs[4][32];

    int t = threadIdx.x;
    int w = t >> 6, lane = t & 63;
    int row, hf;
    attn_map2(blockIdx.x, w, row, hf);
    int bbase = (row >> 13) << 13;

    int c4 = lane & 15;     // dim chunk within half (8 dims each)
    int jg = lane >> 4;     // neighbour group 0..3 (8 nbrs each)

    if (lane < 32) {
        int ji = nbr[(size_t)row * 32 + lane];
        jbs[w][lane] = (bbase + ji) * 256 + hf * 128;
    }

    // Q (bf16) unpack once into packed pairs
    f32x2 q2[4];
    {
        uint4 qw = *reinterpret_cast<const uint4*>(Qh + (size_t)row * 256 + hf * 128 + c4 * 8);
        float qa[8];
        up2(qw.x, qa[0], qa[1]); up2(qw.y, qa[2], qa[3]);
        up2(qw.z, qa[4], qa[5]); up2(qw.w, qa[6], qa[7]);
#pragma unroll
        for (int j = 0; j < 4; ++j) { q2[j].x = qa[2 * j]; q2[j].y = qa[2 * j + 1]; }
    }

    int off[8];
#pragma unroll
    for (int u = 0; u < 8; ++u) off[u] = jbs[w][jg * 8 + u];

    // scores: f32 K, packed-pair FMA, per-head dot via xor 1,2
    float e8[8];
#pragma unroll
    for (int u = 0; u < 8; ++u) {
        const float4* kp = reinterpret_cast<const float4*>(Khf + (size_t)off[u] + c4 * 8);
        float4 ka = kp[0], kb = kp[1];
        f32x2 k0, k1, k2, k3;
        k0.x = ka.x; k0.y = ka.y; k1.x = ka.z; k1.y = ka.w;
        k2.x = kb.x; k2.y = kb.y; k3.x = kb.z; k3.y = kb.w;
        f32x2 p2 = q2[0] * k0;
        p2 += q2[1] * k1;
        p2 += q2[2] * k2;
        p2 += q2[3] * k3;
        float p = p2.x + p2.y;
        p += __shfl_xor(p, 1);
        p += __shfl_xor(p, 2);
        e8[u] = p * 0.0625f;
    }

    // per-head softmax over 32 nbrs (8 local + cross-group via xor 16,32)
    float m = e8[0];
#pragma unroll
    for (int jj = 1; jj < 8; ++jj) m = fmaxf(m, e8[jj]);
    m = fmaxf(m, __shfl_xor(m, 16));
    m = fmaxf(m, __shfl_xor(m, 32));
    float s = 0.f;
#pragma unroll
    for (int jj = 0; jj < 8; ++jj) { e8[jj] = __expf(e8[jj] - m); s += e8[jj]; }
    s += __shfl_xor(s, 16);
    s += __shfl_xor(s, 32);
    float rs = 1.0f / s;

    // weighted V accumulate: f32 V, packed-pair FMA
    f32x2 a2[4] = {};
#pragma unroll
    for (int u = 0; u < 8; ++u) {
        const float4* vp = reinterpret_cast<const float4*>(Vhf + (size_t)off[u] + c4 * 8);
        float4 va = vp[0], vb = vp[1];
        float wgt = e8[u] * rs;
        f32x2 w2; w2.x = wgt; w2.y = wgt;
        f32x2 v0, v1, v2, v3;
        v0.x = va.x; v0.y = va.y; v1.x = va.z; v1.y = va.w;
        v2.x = vb.x; v2.y = vb.y; v3.x = vb.z; v3.y = vb.w;
        a2[0] += w2 * v0;
        a2[1] += w2 * v1;
        a2[2] += w2 * v2;
        a2[3] += w2 * v3;
    }

    float acc[8];
#pragma unroll
    for (int j = 0; j < 4; ++j) { acc[2 * j] = a2[j].x; acc[2 * j + 1] = a2[j].y; }
#pragma unroll
    for (int u = 0; u < 8; ++u) {
        acc[u] += __shfl_xor(acc[u], 16);
        acc[u] += __shfl_xor(acc[u], 32);
    }

    if (lane < 16) {   // jg == 0
        union { __hip_bfloat162 h2[4]; uint4 u4; } o;
        o.h2[0] = __float22bfloat162_rn(make_float2(acc[0], acc[1]));
        o.h2[1] = __float22bfloat162_rn(make_float2(acc[2], acc[3]));
        o.h2[2] = __float22bfloat162_rn(make_float2(acc[4], acc[5]));
        o.h2[3] = __float22bfloat162_rn(make_float2(acc[6], acc[7]));
        *reinterpret_cast<uint4*>(AVb + (size_t)row * 256 + hf * 128 + c4 * 8) = o.u4;
    }
}

// ---------------------------------------------------------------------------
extern "C" void kernel_launch(void* const* d_in, const int* in_sizes, int n_in,
                              void* d_out, int out_size, void* d_ws, size_t ws_size,
                              hipStream_t stream) {
    const float* Q   = (const float*)d_in[0];
    const float* K   = (const float*)d_in[1];
    const int*   nbr = (const int*)d_in[2];
    const float* Wq  = (const float*)d_in[3];
    const float* bq  = (const float*)d_in[4];
    const float* Wk  = (const float*)d_in[5];
    const float* bk  = (const float*)d_in[6];
    const float* Wv  = (const float*)d_in[7];
    const float* bv  = (const float*)d_in[8];
    const float* Wo  = (const float*)d_in[9];
    const float* bo  = (const float*)d_in[10];
    float* out = (float*)d_out;

    char* ws = (char*)d_ws;
    size_t off = 0;
    auto alloc = [&](size_t bytes) -> void* {
        void* p = ws + off;
        off += (bytes + 255) & ~(size_t)255;
        return p;
    };
    const size_t MN = 16384;
    u16*   Wtq = (u16*)alloc(256 * 256 * 2);
    u16*   Wtk = (u16*)alloc(256 * 256 * 2);
    u16*   Wtv = (u16*)alloc(256 * 256 * 2);
    u16*   Wto = (u16*)alloc(256 * 256 * 2);
    u16*   Qh  = (u16*)alloc(MN * 256 * 2);
    float* Khf = (float*)alloc(MN * 256 * 4);
    float* Vhf = (float*)alloc(MN * 256 * 4);
    u16*   AVb = (u16*)alloc(MN * 256 * 2);

    wprep<<<dim3(4, 4, 4), 256, 0, stream>>>(Wq, Wk, Wv, Wo, Wtq, Wtk, Wtv, Wto);
    gemm_proj<<<dim3(256, 1, 3), 256, 0, stream>>>(Q, K, Wtq, Wtk, Wtv,
                                                   bq, bk, bv, Qh, Khf, Vhf);
    attn_fused<<<dim3(8192), 256, 0, stream>>>(Qh, Khf, Vhf, nbr, AVb);
    gemm_out<<<dim3(256, 2), 256, 0, stream>>>(AVb, Wto, bo, out);
}

// Round 12
// 149.617 us; speedup vs baseline: 1.2839x; 1.2839x over previous
//
#include <hip/hip_runtime.h>
#include <hip/hip_bf16.h>
#include <stdint.h>

typedef unsigned short u16;
typedef __attribute__((ext_vector_type(8))) short short8;
typedef __attribute__((ext_vector_type(4))) float f32x4;

__device__ __forceinline__ u16 f2bf(float f) {
    union { float f; unsigned int i; } v; v.f = f;
    unsigned int b = v.i;
    return (u16)((b + 0x7FFFu + ((b >> 16) & 1u)) >> 16);
}

// float -> f16 bits (RTE)
__device__ __forceinline__ u16 f2h(float f) {
    _Float16 h = (_Float16)f;
    union { _Float16 h; u16 u; } c; c.h = h;
    return c.u;
}

// f16 bits -> float (clang fuses (float)h into v_fma_mix when consumed by fmaf)
__device__ __forceinline__ float h2f(u16 x) {
    union { u16 u; _Float16 h; } c; c.u = x;
    return (float)c.h;
}

__device__ __forceinline__ short8 cvt8(float4 a, float4 b) {
    union { __hip_bfloat162 h[4]; short8 s; } u;
    u.h[0] = __float22bfloat162_rn(make_float2(a.x, a.y));
    u.h[1] = __float22bfloat162_rn(make_float2(a.z, a.w));
    u.h[2] = __float22bfloat162_rn(make_float2(b.x, b.y));
    u.h[3] = __float22bfloat162_rn(make_float2(b.z, b.w));
    return u.s;
}

typedef const __attribute__((address_space(1))) void* as1cv;
typedef __attribute__((address_space(3))) void* as3v;
__device__ __forceinline__ void gload16(const void* g, void* l) {
    __builtin_amdgcn_global_load_lds((as1cv)g, (as3v)l, 16, 0, 0);
}

__device__ __forceinline__ void up2(unsigned int v, float& lo, float& hi) {
    union { unsigned int i; float f; } a, b;
    a.i = v << 16; b.i = v & 0xffff0000u;
    lo = a.f; hi = b.f;
}

// ---------------------------------------------------------------------------
// wprep: weight convert fp32 -> bf16, transposed. (verbatim R13, known-good)
// ---------------------------------------------------------------------------
__global__ __launch_bounds__(256) void wprep(
    const float* __restrict__ W0, const float* __restrict__ W1,
    const float* __restrict__ W2, const float* __restrict__ W3,
    u16* __restrict__ T0, u16* __restrict__ T1,
    u16* __restrict__ T2, u16* __restrict__ T3)
{
    const float* W = blockIdx.z == 0 ? W0 : blockIdx.z == 1 ? W1 : blockIdx.z == 2 ? W2 : W3;
    u16*        T  = blockIdx.z == 0 ? T0 : blockIdx.z == 1 ? T1 : blockIdx.z == 2 ? T2 : T3;
    __shared__ u16 ts[64][65];
    int k0 = blockIdx.x * 64, n0 = blockIdx.y * 64;
    int t = threadIdx.x;
    int r = t >> 2, cq = (t & 3) * 16;
    const float4* src = reinterpret_cast<const float4*>(W + (k0 + r) * 256 + n0 + cq);
    for (int u = 0; u < 4; ++u) {
        float4 v = src[u];
        int c = cq + u * 4;
        ts[r][c + 0] = f2bf(v.x); ts[r][c + 1] = f2bf(v.y);
        ts[r][c + 2] = f2bf(v.z); ts[r][c + 3] = f2bf(v.w);
    }
    __syncthreads();
    u16* dst = T + (n0 + r) * 256 + k0 + cq;
    for (int u = 0; u < 16; ++u) dst[u] = ts[cq + u][r];
}

// ---------------------------------------------------------------------------
// gemm_proj (R22): R13 tile (BM=64, BN=256, BK=64). Epilogue: Q -> bf16
// (feeds nothing precision-critical downstream of attn unpack-once), K/V ->
// F16 bits in the same u16 buffers (same bytes/FETCH as bf16; more mantissa;
// enables v_fma_mix in attn).
// ---------------------------------------------------------------------------
__global__ __launch_bounds__(256) void gemm_proj(
    const float* __restrict__ Q, const float* __restrict__ K,
    const u16* __restrict__ Wtq, const u16* __restrict__ Wtk, const u16* __restrict__ Wtv,
    const float* __restrict__ bq, const float* __restrict__ bk, const float* __restrict__ bv,
    u16* __restrict__ Qh, u16* __restrict__ Kh, u16* __restrict__ Vh)
{
    int z = blockIdx.z;
    const float* Af   = (z == 0) ? Q   : K;
    const u16*   Wt   = (z == 0) ? Wtq : (z == 1) ? Wtk : Wtv;
    const float* bias = (z == 0) ? bq  : (z == 1) ? bk  : bv;
    u16*         C    = (z == 0) ? Qh  : (z == 1) ? Kh  : Vh;

    __shared__ float Asf[64 * 64];    // 16 KB
    __shared__ u16   Bs[256 * 64];    // 32 KB

    int t = threadIdx.x;
    int lane = t & 63, w = t >> 6;
    int row0 = blockIdx.x * 64;
    int wr = (w >> 1) * 32, wc = (w & 1) * 128;
    int qd = lane >> 4, md = lane & 15;

    f32x4 acc[2][8] = {};

    for (int kt = 0; kt < 256; kt += 64) {
#pragma unroll
        for (int u = 0; u < 4; ++u) {
            int chunk = w * 4 + u;
            int s = chunk * 64 + lane;
            int r = s >> 4, c = s & 15;
            gload16(Af + (size_t)(row0 + r) * 256 + kt + ((c ^ (r & 15)) * 4),
                    (char*)Asf + chunk * 1024);
        }
#pragma unroll
        for (int u = 0; u < 8; ++u) {
            int chunk = w * 8 + u;
            int s = chunk * 64 + lane;
            int r = s >> 3, c = s & 7;
            gload16(Wt + (size_t)r * 256 + kt + ((c ^ (r & 7)) * 8),
                    (char*)Bs + chunk * 1024);
        }
        __syncthreads();
#pragma unroll
        for (int ks = 0; ks < 64; ks += 32) {
            short8 af[2], bf[8];
#pragma unroll
            for (int i = 0; i < 2; ++i) {
                int ar = wr + i * 16 + md;
                int c0 = (ks >> 2) + qd * 2;
                int xx = ar & 15;
                float4 fa0 = reinterpret_cast<const float4*>(Asf)[ar * 16 + (c0 ^ xx)];
                float4 fa1 = reinterpret_cast<const float4*>(Asf)[ar * 16 + ((c0 + 1) ^ xx)];
                af[i] = cvt8(fa0, fa1);
            }
#pragma unroll
            for (int j = 0; j < 8; ++j) {
                int br = wc + j * 16 + md;
                int slot = ((ks >> 3) + qd) ^ (br & 7);
                bf[j] = reinterpret_cast<const short8*>(Bs)[br * 8 + slot];
            }
#pragma unroll
            for (int i = 0; i < 2; ++i)
#pragma unroll
                for (int j = 0; j < 8; ++j)
                    acc[i][j] = __builtin_amdgcn_mfma_f32_16x16x32_bf16(
                        af[i], bf[j], acc[i][j], 0, 0, 0);
        }
        __syncthreads();
    }

#pragma unroll
    for (int i = 0; i < 2; ++i)
#pragma unroll
        for (int j = 0; j < 8; ++j) {
            int col = wc + j * 16 + md;
            float b = bias[col];
#pragma unroll
            for (int r = 0; r < 4; ++r) {
                int row = row0 + wr + i * 16 + qd * 4 + r;
                float v = acc[i][j][r] + b;
                C[(size_t)row * 256 + col] = (z == 0) ? f2bf(v) : f2h(v);
            }
        }
}

// ---------------------------------------------------------------------------
// gemm_out: f32 C = bf16 A @ Wt^T + bias. 64x128 tile. (verbatim R13)
// ---------------------------------------------------------------------------
__global__ __launch_bounds__(256) void gemm_out(
    const u16* __restrict__ Ab, const u16* __restrict__ Wt,
    const float* __restrict__ bias, float* __restrict__ Cout)
{
    __shared__ u16 As[64 * 64];
    __shared__ u16 Bs[128 * 64];

    int t = threadIdx.x;
    int lane = t & 63, w = t >> 6;
    int row0 = blockIdx.x * 64, col0 = blockIdx.y * 128;
    int wr = (w >> 1) * 32, wc = (w & 1) * 64;
    int qd = lane >> 4, md = lane & 15;

    f32x4 acc[2][4] = {};

    for (int kt = 0; kt < 256; kt += 64) {
#pragma unroll
        for (int u = 0; u < 2; ++u) {
            int chunk = w * 2 + u;
            int s = chunk * 64 + lane;
            int r = s >> 3, c = s & 7;
            gload16(Ab + (size_t)(row0 + r) * 256 + kt + ((c ^ (r & 7)) * 8),
                    (char*)As + chunk * 1024);
        }
#pragma unroll
        for (int u = 0; u < 4; ++u) {
            int chunk = w * 4 + u;
            int s = chunk * 64 + lane;
            int r = s >> 3, c = s & 7;
            gload16(Wt + (size_t)(col0 + r) * 256 + kt + ((c ^ (r & 7)) * 8),
                    (char*)Bs + chunk * 1024);
        }
        __syncthreads();
#pragma unroll
        for (int ks = 0; ks < 64; ks += 32) {
            short8 af[2], bf[4];
#pragma unroll
            for (int i = 0; i < 2; ++i) {
                int ar = wr + i * 16 + md;
                int slot = ((ks >> 3) + qd) ^ (ar & 7);
                af[i] = reinterpret_cast<const short8*>(As)[ar * 8 + slot];
            }
#pragma unroll
            for (int j = 0; j < 4; ++j) {
                int br = wc + j * 16 + md;
                int slot = ((ks >> 3) + qd) ^ (br & 7);
                bf[j] = reinterpret_cast<const short8*>(Bs)[br * 8 + slot];
            }
#pragma unroll
            for (int i = 0; i < 2; ++i)
#pragma unroll
                for (int j = 0; j < 4; ++j)
                    acc[i][j] = __builtin_amdgcn_mfma_f32_16x16x32_bf16(
                        af[i], bf[j], acc[i][j], 0, 0, 0);
        }
        __syncthreads();
    }

#pragma unroll
    for (int i = 0; i < 2; ++i)
#pragma unroll
        for (int j = 0; j < 4; ++j) {
            int col = col0 + wc + j * 16 + md;
            float b = bias[col];
#pragma unroll
            for (int r = 0; r < 4; ++r) {
                int row = row0 + wr + i * 16 + qd * 4 + r;
                Cout[(size_t)row * 256 + col] = acc[i][j][r] + b;
            }
        }
}

// ---------------------------------------------------------------------------
// attn row mapping: (batch, head-half) classes spread 2 XCDs each. (R13)
// ---------------------------------------------------------------------------
__device__ __forceinline__ void attn_map2(int blk, int w, int& row, int& hf) {
    int g = blk & 7;
    int batch = g >> 2;
    hf = (g >> 1) & 1;
    int cb = (blk >> 3) * 2 + (g & 1);
    row = batch * 8192 + cb * 4 + w;
}

// ---------------------------------------------------------------------------
// attn_fused (R22): R13 structure + F16 K/V consumed via (float)_Float16
// inside fmaf — clang emits v_fma_mix_f32 (inline f16->f32 operand), halving
// the unpack+fma core (R20: VALU-bound at 87% busy; R21 proved the VALU cut
// works but f32 gathers blew L2 — f16 keeps 16-bit gather width).
// ---------------------------------------------------------------------------
__global__ __launch_bounds__(256) void attn_fused(
    const u16* __restrict__ Qh, const u16* __restrict__ Kh,
    const u16* __restrict__ Vh, const int* __restrict__ nbr,
    u16* __restrict__ AVb)
{
    __shared__ int jbs[4][32];

    int t = threadIdx.x;
    int w = t >> 6, lane = t & 63;
    int row, hf;
    attn_map2(blockIdx.x, w, row, hf);
    int bbase = (row >> 13) << 13;

    int c4 = lane & 15;     // dim chunk within half (8 dims each)
    int jg = lane >> 4;     // neighbour group 0..3 (8 nbrs each)

    if (lane < 32) {
        int ji = nbr[(size_t)row * 32 + lane];
        jbs[w][lane] = (bbase + ji) * 256 + hf * 128;
    }

    float qf[8];
    {
        uint4 qw = *reinterpret_cast<const uint4*>(Qh + (size_t)row * 256 + hf * 128 + c4 * 8);
        up2(qw.x, qf[0], qf[1]); up2(qw.y, qf[2], qf[3]);
        up2(qw.z, qf[4], qf[5]); up2(qw.w, qf[6], qf[7]);
    }

    int off[8];
#pragma unroll
    for (int u = 0; u < 8; ++u) off[u] = jbs[w][jg * 8 + u];

    uint4 kw[8];
#pragma unroll
    for (int u = 0; u < 8; ++u)
        kw[u] = *reinterpret_cast<const uint4*>(Kh + (size_t)off[u] + c4 * 8);

    uint4 vv[8];
#pragma unroll
    for (int u = 0; u < 8; ++u)
        vv[u] = *reinterpret_cast<const uint4*>(Vh + (size_t)off[u] + c4 * 8);

    // scores: fma_mix core — one op per (q, k16) pair
    float e8[8];
#pragma unroll
    for (int u = 0; u < 8; ++u) {
        union { uint4 u4; u16 us[8]; } ku; ku.u4 = kw[u];
        float p = 0.f;
#pragma unroll
        for (int j = 0; j < 8; ++j) p = fmaf(qf[j], h2f(ku.us[j]), p);
        p += __shfl_xor(p, 1);
        p += __shfl_xor(p, 2);
        e8[u] = p * 0.0625f;
    }

    // per-head softmax over 32 nbrs (8 local + cross-group via xor 16,32)
    float m = e8[0];
#pragma unroll
    for (int jj = 1; jj < 8; ++jj) m = fmaxf(m, e8[jj]);
    m = fmaxf(m, __shfl_xor(m, 16));
    m = fmaxf(m, __shfl_xor(m, 32));
    float s = 0.f;
#pragma unroll
    for (int jj = 0; jj < 8; ++jj) { e8[jj] = __expf(e8[jj] - m); s += e8[jj]; }
    s += __shfl_xor(s, 16);
    s += __shfl_xor(s, 32);
    float rs = 1.0f / s;

    // weighted V accumulate: fma_mix core
    float acc[8] = {};
#pragma unroll
    for (int u = 0; u < 8; ++u) {
        union { uint4 u4; u16 us[8]; } vu; vu.u4 = vv[u];
        float wgt = e8[u] * rs;
#pragma unroll
        for (int j = 0; j < 8; ++j) acc[j] = fmaf(wgt, h2f(vu.us[j]), acc[j]);
    }
#pragma unroll
    for (int u = 0; u < 8; ++u) {
        acc[u] += __shfl_xor(acc[u], 16);
        acc[u] += __shfl_xor(acc[u], 32);
    }

    if (lane < 16) {   // jg == 0
        union { __hip_bfloat162 h2[4]; uint4 u4; } o;
        o.h2[0] = __float22bfloat162_rn(make_float2(acc[0], acc[1]));
        o.h2[1] = __float22bfloat162_rn(make_float2(acc[2], acc[3]));
        o.h2[2] = __float22bfloat162_rn(make_float2(acc[4], acc[5]));
        o.h2[3] = __float22bfloat162_rn(make_float2(acc[6], acc[7]));
        *reinterpret_cast<uint4*>(AVb + (size_t)row * 256 + hf * 128 + c4 * 8) = o.u4;
    }
}

// ---------------------------------------------------------------------------
extern "C" void kernel_launch(void* const* d_in, const int* in_sizes, int n_in,
                              void* d_out, int out_size, void* d_ws, size_t ws_size,
                              hipStream_t stream) {
    const float* Q   = (const float*)d_in[0];
    const float* K   = (const float*)d_in[1];
    const int*   nbr = (const int*)d_in[2];
    const float* Wq  = (const float*)d_in[3];
    const float* bq  = (const float*)d_in[4];
    const float* Wk  = (const float*)d_in[5];
    const float* bk  = (const float*)d_in[6];
    const float* Wv  = (const float*)d_in[7];
    const float* bv  = (const float*)d_in[8];
    const float* Wo  = (const float*)d_in[9];
    const float* bo  = (const float*)d_in[10];
    float* out = (float*)d_out;

    char* ws = (char*)d_ws;
    size_t off = 0;
    auto alloc = [&](size_t bytes) -> void* {
        void* p = ws + off;
        off += (bytes + 255) & ~(size_t)255;
        return p;
    };
    const size_t MN = 16384;
    u16* Wtq = (u16*)alloc(256 * 256 * 2);
    u16* Wtk = (u16*)alloc(256 * 256 * 2);
    u16* Wtv = (u16*)alloc(256 * 256 * 2);
    u16* Wto = (u16*)alloc(256 * 256 * 2);
    u16* Qh  = (u16*)alloc(MN * 256 * 2);
    u16* Kh  = (u16*)alloc(MN * 256 * 2);
    u16* Vh  = (u16*)alloc(MN * 256 * 2);
    u16* AVb = (u16*)alloc(MN * 256 * 2);

    wprep<<<dim3(4, 4, 4), 256, 0, stream>>>(Wq, Wk, Wv, Wo, Wtq, Wtk, Wtv, Wto);
    gemm_proj<<<dim3(256, 1, 3), 256, 0, stream>>>(Q, K, Wtq, Wtk, Wtv,
                                                   bq, bk, bv, Qh, Kh, Vh);
    attn_fused<<<dim3(8192), 256, 0, stream>>>(Qh, Kh, Vh, nbr, AVb);
    gemm_out<<<dim3(256, 2), 256, 0, stream>>>(AVb, Wto, bo, out);
}